// Round 3
// baseline (1200.935 us; speedup 1.0000x reference)
//
#include <hip/hip_runtime.h>
#include <hip/hip_bf16.h>
#include <stdint.h>

#define NTOK 32768
#define DIM  768
#define HID  256
#define NEXP 8

typedef float f32x4 __attribute__((ext_vector_type(4)));
typedef short s16x8 __attribute__((ext_vector_type(8)));

__device__ __forceinline__ unsigned short f2bf(float f) {
  union { float f; unsigned int u; } c; c.f = f;
  unsigned int r = c.u + 0x7fffu + ((c.u >> 16) & 1u);
  return (unsigned short)(r >> 16);
}

// ---------------- x fp32 -> bf16 ----------------
__global__ __launch_bounds__(256) void k_cvt_x(const float* __restrict__ x,
                                               unsigned short* __restrict__ xbf) {
  int i = (blockIdx.x * 256 + threadIdx.x) * 8;
  float4 a = *(const float4*)(x + i);
  float4 b = *(const float4*)(x + i + 4);
  unsigned int p0 = (unsigned int)f2bf(a.x) | ((unsigned int)f2bf(a.y) << 16);
  unsigned int p1 = (unsigned int)f2bf(a.z) | ((unsigned int)f2bf(a.w) << 16);
  unsigned int p2 = (unsigned int)f2bf(b.x) | ((unsigned int)f2bf(b.y) << 16);
  unsigned int p3 = (unsigned int)f2bf(b.z) | ((unsigned int)f2bf(b.w) << 16);
  int4 v; v.x = (int)p0; v.y = (int)p1; v.z = (int)p2; v.w = (int)p3;
  *(int4*)(xbf + i) = v;
}

// ---------------- fp32 [R][C] -> bf16 [C][R] transpose via LDS tile ----------------
__global__ __launch_bounds__(256) void k_tr(const float* __restrict__ in,
                                            unsigned short* __restrict__ outp,
                                            int R, int C) {
  __shared__ float tile[32][33];
  int e = blockIdx.z;
  const float* ip = in + (size_t)e * R * C;
  unsigned short* op = outp + (size_t)e * R * C;
  int tx = threadIdx.x & 31, ty = threadIdx.x >> 5;  // 32x8
  int r0 = blockIdx.y * 32, c0 = blockIdx.x * 32;
#pragma unroll
  for (int i = 0; i < 4; ++i)
    tile[ty + i * 8][tx] = ip[(size_t)(r0 + ty + i * 8) * C + c0 + tx];
  __syncthreads();
#pragma unroll
  for (int i = 0; i < 4; ++i)
    op[(size_t)(c0 + ty + i * 8) * R + r0 + tx] = f2bf(tile[tx][ty + i * 8]);
}

// ---------------- gate layer 1: hg = relu(x @ Wg1 + bg1), fp32 SGEMM ----------------
__global__ __launch_bounds__(256) void k_gate1(const float* __restrict__ x,
                                               const float* __restrict__ wg1,
                                               const float* __restrict__ bg1,
                                               float* __restrict__ hg) {
  __shared__ __align__(16) float As[16][132];
  __shared__ __align__(16) float Bs[16][64];
  int bm = blockIdx.x * 128;
  int bn = blockIdx.y * 64;
  int tid = threadIdx.x;
  int tx = tid & 15, ty = tid >> 4;
  f32x4 acc[8] = {};
  for (int k0 = 0; k0 < DIM; k0 += 16) {
#pragma unroll
    for (int l = 0; l < 2; ++l) {
      int i4 = tid + l * 256;
      int row = i4 >> 2;
      int kq = (i4 & 3) * 4;
      float4 v = *(const float4*)&x[(bm + row) * DIM + k0 + kq];
      As[kq + 0][row] = v.x; As[kq + 1][row] = v.y;
      As[kq + 2][row] = v.z; As[kq + 3][row] = v.w;
    }
    {
      int krow = tid >> 4;
      int c4 = (tid & 15) * 4;
      *(float4*)&Bs[krow][c4] = *(const float4*)&wg1[(k0 + krow) * HID + bn + c4];
    }
    __syncthreads();
#pragma unroll
    for (int kk = 0; kk < 16; ++kk) {
      f32x4 a0 = *(const f32x4*)&As[kk][ty * 8];
      f32x4 a1 = *(const f32x4*)&As[kk][ty * 8 + 4];
      f32x4 bv = *(const f32x4*)&Bs[kk][tx * 4];
#pragma unroll
      for (int i = 0; i < 4; ++i) acc[i]     += bv * a0[i];
#pragma unroll
      for (int i = 0; i < 4; ++i) acc[i + 4] += bv * a1[i];
    }
    __syncthreads();
  }
  f32x4 bias = *(const f32x4*)&bg1[bn + tx * 4];
#pragma unroll
  for (int i = 0; i < 8; ++i) {
    f32x4 v = acc[i] + bias;
#pragma unroll
    for (int j = 0; j < 4; ++j) v[j] = fmaxf(v[j], 0.f);
    *(f32x4*)&hg[(bm + ty * 8 + i) * HID + bn + tx * 4] = v;
  }
}

// ---------------- gate layer 2 + softmax + top2 + routing lists ----------------
__global__ __launch_bounds__(256) void k_gate2(const float* __restrict__ hg,
                                               const float* __restrict__ wg2,
                                               const float* __restrict__ bg2,
                                               float* __restrict__ gprob,
                                               int* __restrict__ cnt,     // stride 32
                                               int* __restrict__ lists,
                                               float* __restrict__ wts) {
  __shared__ int lcnt[8];
  __shared__ int sbase[8];
  __shared__ int se1[256], se2[256], sp1[256], sp2[256];
  __shared__ float sw1[256], sw2[256];
  int tid = threadIdx.x;
  if (tid < 8) lcnt[tid] = 0;
  __syncthreads();

  int tok = blockIdx.x * 256 + tid;
  const float* hrow = hg + (size_t)tok * HID;

  float s[8];
#pragma unroll
  for (int e = 0; e < 8; ++e) s[e] = bg2[e];
#pragma unroll 8
  for (int j = 0; j < 64; ++j) {
    f32x4 hv = *(const f32x4*)(hrow + j * 4);
#pragma unroll
    for (int i = 0; i < 4; ++i) {
      const float* wr = wg2 + (j * 4 + i) * 8;
#pragma unroll
      for (int e = 0; e < 8; ++e) s[e] += hv[i] * wr[e];
    }
  }

  float m = s[0];
#pragma unroll
  for (int e = 1; e < 8; ++e) m = fmaxf(m, s[e]);
  float p[8]; float sum = 0.f;
#pragma unroll
  for (int e = 0; e < 8; ++e) { p[e] = expf(s[e] - m); sum += p[e]; }
  float inv = 1.f / sum;
#pragma unroll
  for (int e = 0; e < 8; ++e) p[e] *= inv;

  f32x4 o0 = {p[0], p[1], p[2], p[3]};
  f32x4 o1 = {p[4], p[5], p[6], p[7]};
  *(f32x4*)&gprob[(size_t)tok * 8] = o0;
  *(f32x4*)&gprob[(size_t)tok * 8 + 4] = o1;

  int e1 = 0; float p1 = p[0];
#pragma unroll
  for (int e = 1; e < 8; ++e) if (p[e] > p1) { p1 = p[e]; e1 = e; }
  int e2 = -1; float p2 = -1.f;
#pragma unroll
  for (int e = 0; e < 8; ++e) if (e != e1 && p[e] > p2) { p2 = p[e]; e2 = e; }
  float rinv = 1.f / (p1 + p2);

  int pos1 = atomicAdd(&lcnt[e1], 1);
  int pos2 = atomicAdd(&lcnt[e2], 1);
  se1[tid] = e1; sp1[tid] = pos1; sw1[tid] = p1 * rinv;
  se2[tid] = e2; sp2[tid] = pos2; sw2[tid] = p2 * rinv;
  __syncthreads();

  if (tid < 8) sbase[tid] = atomicAdd(&cnt[tid * 32], lcnt[tid]);
  __syncthreads();

  int a1i = sbase[se1[tid]] + sp1[tid];
  lists[se1[tid] * NTOK + a1i] = tok; wts[se1[tid] * NTOK + a1i] = sw1[tid];
  int a2i = sbase[se2[tid]] + sp2[tid];
  lists[se2[tid] * NTOK + a2i] = tok; wts[se2[tid] * NTOK + a2i] = sw2[tid];
}

// ---------------- fused routed expert FFN (weights from L2, no W staging) ----------------
// 1D grid, expert = bid & 7 so round-robin block->XCD keeps one expert's weights per XCD L2.
// LDS: x-tile double buffer (16KB) + h (32KB) = 48KB -> 3 blocks/CU.
__global__ __launch_bounds__(256) void k_expert(const unsigned short* __restrict__ xbf,
                                                const unsigned short* __restrict__ w1t,
                                                const unsigned short* __restrict__ w2t,
                                                const float* __restrict__ b1,
                                                const float* __restrict__ b2,
                                                const int* __restrict__ cnt,
                                                const int* __restrict__ lists,
                                                const float* __restrict__ wts,
                                                float* __restrict__ out) {
  int bid = blockIdx.x;
  int e = bid & 7;
  int tile = bid >> 3;
  int c = cnt[e * 32];
  int row0 = tile * 64;
  if (row0 >= c) return;

  __shared__ __align__(16) unsigned short xs[2][64 * 64];  // 16KB double-buffered
  __shared__ __align__(16) unsigned short hs[64 * 256];    // 32KB
  __shared__ int stok[64];
  __shared__ float swt[64];

  int tid = threadIdx.x;
  int lane = tid & 63;
  int wid = tid >> 6;
  int ar = lane & 15;
  int kg = lane >> 4;  // 0..3

  if (tid < 64) {
    int r = row0 + tid;
    stok[tid] = (r < c) ? lists[e * NTOK + r] : lists[e * NTOK];
    swt[tid]  = (r < c) ? wts[e * NTOK + r] : 0.f;
  }
  __syncthreads();

  // gathered, pre-swizzled x staging sources: 2 x 16B per thread per K-step
  const unsigned short* xsrc[2];
#pragma unroll
  for (int q = 0; q < 2; ++q) {
    int ci = tid + q * 256;
    int row = ci >> 3, cb = ci & 7;
    xsrc[q] = xbf + (size_t)stok[row] * DIM + ((cb ^ (row & 7)) * 8);
  }

  const unsigned short* w1e = w1t + (size_t)e * HID * DIM;
  const unsigned short* w1row[4];
#pragma unroll
  for (int n = 0; n < 4; ++n)
    w1row[n] = w1e + (size_t)(wid * 64 + n * 16 + ar) * DIM + kg * 8;

  f32x4 acc[4][4] = {};

  // prologue: stage kt=0 into buf 0
  {
    int4 v0 = *(const int4*)(xsrc[0]);
    int4 v1 = *(const int4*)(xsrc[1]);
    *(int4*)&xs[0][tid * 8] = v0;
    *(int4*)&xs[0][(tid + 256) * 8] = v1;
  }
  __syncthreads();

  // ---- layer 1: h = relu(x @ W1 + b1), K = 768, BK = 64, one barrier per step ----
  for (int kt = 0; kt < DIM / 64; ++kt) {
    int cur = kt & 1;
    int4 nv0, nv1;
    if (kt < 11) {  // issue next-tile loads; they fly during this step's MFMAs
      nv0 = *(const int4*)(xsrc[0] + (kt + 1) * 64);
      nv1 = *(const int4*)(xsrc[1] + (kt + 1) * 64);
    }
#pragma unroll
    for (int ks = 0; ks < 2; ++ks) {
      int kc = ks * 4 + kg;
      s16x8 a[4], b[4];
#pragma unroll
      for (int n = 0; n < 4; ++n)
        b[n] = *(const s16x8*)(w1row[n] + kt * 64 + ks * 32);  // L2-resident
#pragma unroll
      for (int m = 0; m < 4; ++m) {
        int row = m * 16 + ar;
        a[m] = *(const s16x8*)&xs[cur][row * 64 + ((kc ^ (ar & 7)) * 8)];
      }
#pragma unroll
      for (int m = 0; m < 4; ++m)
#pragma unroll
        for (int n = 0; n < 4; ++n)
          acc[m][n] = __builtin_amdgcn_mfma_f32_16x16x32_bf16(a[m], b[n], acc[m][n], 0, 0, 0);
    }
    if (kt < 11) {  // write other buffer (safe: everyone finished reading it last step)
      *(int4*)&xs[cur ^ 1][tid * 8] = nv0;
      *(int4*)&xs[cur ^ 1][(tid + 256) * 8] = nv1;
    }
    __syncthreads();
  }

  // bias + relu -> hs (bf16, swizzled)
#pragma unroll
  for (int n = 0; n < 4; ++n) {
    int col = wid * 64 + n * 16 + ar;
    float bb = b1[e * HID + col];
#pragma unroll
    for (int m = 0; m < 4; ++m) {
#pragma unroll
      for (int r = 0; r < 4; ++r) {
        int tr = m * 16 + kg * 4 + r;
        float v = fmaxf(acc[m][n][r] + bb, 0.f);
        hs[tr * HID + (((col >> 3) ^ (tr & 7)) * 8) + (col & 7)] = f2bf(v);
      }
    }
  }
  __syncthreads();

  // hoist per-thread token ids / weights (skip atomics for pad rows: swt==0)
  float sw16[4][4]; int st16[4][4];
#pragma unroll
  for (int m = 0; m < 4; ++m)
#pragma unroll
    for (int r = 0; r < 4; ++r) {
      int tr = m * 16 + kg * 4 + r;
      sw16[m][r] = swt[tr];
      st16[m][r] = stok[tr];
    }

  const unsigned short* w2e = w2t + (size_t)e * DIM * HID;

  // ---- layer 2: out += wt * (h @ W2 + b2); barrier-free, B from L2, A from hs ----
#pragma unroll 1
  for (int p = 0; p < 3; ++p) {
#pragma unroll
    for (int m = 0; m < 4; ++m)
#pragma unroll
      for (int n = 0; n < 4; ++n) acc[m][n] = (f32x4){0.f, 0.f, 0.f, 0.f};
    const unsigned short* w2row[4];
#pragma unroll
    for (int n = 0; n < 4; ++n)
      w2row[n] = w2e + (size_t)(p * HID + wid * 64 + n * 16 + ar) * HID + kg * 8;
#pragma unroll 2
    for (int kst = 0; kst < 8; ++kst) {
      int kch = kst * 4 + kg;
      s16x8 a[4], b[4];
#pragma unroll
      for (int n = 0; n < 4; ++n)
        b[n] = *(const s16x8*)(w2row[n] + kst * 32);
#pragma unroll
      for (int m = 0; m < 4; ++m) {
        int row = m * 16 + ar;
        a[m] = *(const s16x8*)&hs[row * HID + ((kch ^ (ar & 7)) * 8)];
      }
#pragma unroll
      for (int m = 0; m < 4; ++m)
#pragma unroll
        for (int n = 0; n < 4; ++n)
          acc[m][n] = __builtin_amdgcn_mfma_f32_16x16x32_bf16(a[m], b[n], acc[m][n], 0, 0, 0);
    }
#pragma unroll
    for (int n = 0; n < 4; ++n) {
      int col = p * HID + wid * 64 + n * 16 + ar;
      float bb = b2[e * DIM + col];
#pragma unroll
      for (int m = 0; m < 4; ++m) {
#pragma unroll
        for (int r = 0; r < 4; ++r) {
          if (sw16[m][r] != 0.f) {
            float v = (acc[m][n][r] + bb) * sw16[m][r];
            atomicAdd(&out[(size_t)st16[m][r] * DIM + col], v);
          }
        }
      }
    }
  }
}

extern "C" void kernel_launch(void* const* d_in, const int* in_sizes, int n_in,
                              void* d_out, int out_size, void* d_ws, size_t ws_size,
                              hipStream_t stream) {
  const float* x   = (const float*)d_in[0];
  const float* W1  = (const float*)d_in[1];
  const float* b1  = (const float*)d_in[2];
  const float* W2  = (const float*)d_in[3];
  const float* b2  = (const float*)d_in[4];
  const float* Wg1 = (const float*)d_in[5];
  const float* bg1 = (const float*)d_in[6];
  const float* Wg2 = (const float*)d_in[7];
  const float* bg2 = (const float*)d_in[8];
  float* out = (float*)d_out;                       // [N][768] then [N][8]
  float* gprob = out + (size_t)NTOK * DIM;

  char* ws = (char*)d_ws;
  size_t off = 0;
  auto alloc = [&](size_t bytes) { void* pp = ws + off; off += (bytes + 255) & ~(size_t)255; return pp; };
  unsigned short* xbf = (unsigned short*)alloc((size_t)NTOK * DIM * 2);
  unsigned short* w1t = (unsigned short*)alloc((size_t)NEXP * HID * DIM * 2);
  unsigned short* w2t = (unsigned short*)alloc((size_t)NEXP * DIM * HID * 2);
  float* hg = (float*)alloc((size_t)NTOK * HID * 4);
  int* cnt = (int*)alloc(NEXP * 32 * 4);            // 128B-padded counters
  int* lists = (int*)alloc((size_t)NEXP * NTOK * 4);
  float* wts = (float*)alloc((size_t)NEXP * NTOK * 4);

  hipMemsetAsync(d_out, 0, (size_t)NTOK * DIM * sizeof(float), stream);
  hipMemsetAsync(cnt, 0, NEXP * 32 * sizeof(int), stream);

  k_cvt_x<<<(NTOK * DIM) / (256 * 8), 256, 0, stream>>>(x, xbf);
  k_tr<<<dim3(HID / 32, DIM / 32, NEXP), 256, 0, stream>>>(W1, w1t, DIM, HID);  // W1[e][d][h] -> w1t[e][h][d]
  k_tr<<<dim3(DIM / 32, HID / 32, NEXP), 256, 0, stream>>>(W2, w2t, HID, DIM);  // W2[e][h][d] -> w2t[e][d][h]
  k_gate1<<<dim3(NTOK / 128, HID / 64), 256, 0, stream>>>(x, Wg1, bg1, hg);
  k_gate2<<<NTOK / 256, 256, 0, stream>>>(hg, Wg2, bg2, gprob, cnt, lists, wts);
  k_expert<<<(NTOK / 64) * NEXP, 256, 0, stream>>>(xbf, w1t, w2t, b1, b2, cnt, lists, wts, out);
}

// Round 4
// 562.732 us; speedup vs baseline: 2.1341x; 2.1341x over previous
//
#include <hip/hip_runtime.h>
#include <hip/hip_bf16.h>
#include <stdint.h>

#define NTOK 32768
#define DIM  768
#define HID  256
#define NEXP 8

typedef float f32x4 __attribute__((ext_vector_type(4)));
typedef short s16x8 __attribute__((ext_vector_type(8)));

__device__ __forceinline__ unsigned short f2bf(float f) {
  union { float f; unsigned int u; } c; c.f = f;
  unsigned int r = c.u + 0x7fffu + ((c.u >> 16) & 1u);
  return (unsigned short)(r >> 16);
}

// async global -> LDS, 16B per lane. LDS dest is wave-uniform base + lane*16.
__device__ __forceinline__ void gload_lds16(const unsigned short* g, unsigned short* l) {
  __builtin_amdgcn_global_load_lds((const __attribute__((address_space(1))) void*)g,
                                   (__attribute__((address_space(3))) void*)l, 16, 0, 0);
}

// ---------------- x fp32 -> bf16 ----------------
__global__ __launch_bounds__(256) void k_cvt_x(const float* __restrict__ x,
                                               unsigned short* __restrict__ xbf) {
  int i = (blockIdx.x * 256 + threadIdx.x) * 8;
  float4 a = *(const float4*)(x + i);
  float4 b = *(const float4*)(x + i + 4);
  unsigned int p0 = (unsigned int)f2bf(a.x) | ((unsigned int)f2bf(a.y) << 16);
  unsigned int p1 = (unsigned int)f2bf(a.z) | ((unsigned int)f2bf(a.w) << 16);
  unsigned int p2 = (unsigned int)f2bf(b.x) | ((unsigned int)f2bf(b.y) << 16);
  unsigned int p3 = (unsigned int)f2bf(b.z) | ((unsigned int)f2bf(b.w) << 16);
  int4 v; v.x = (int)p0; v.y = (int)p1; v.z = (int)p2; v.w = (int)p3;
  *(int4*)(xbf + i) = v;
}

// ---------------- fp32 [R][C] -> bf16 [C][R] transpose via LDS tile ----------------
__global__ __launch_bounds__(256) void k_tr(const float* __restrict__ in,
                                            unsigned short* __restrict__ outp,
                                            int R, int C) {
  __shared__ float tile[32][33];
  int e = blockIdx.z;
  const float* ip = in + (size_t)e * R * C;
  unsigned short* op = outp + (size_t)e * R * C;
  int tx = threadIdx.x & 31, ty = threadIdx.x >> 5;  // 32x8
  int r0 = blockIdx.y * 32, c0 = blockIdx.x * 32;
#pragma unroll
  for (int i = 0; i < 4; ++i)
    tile[ty + i * 8][tx] = ip[(size_t)(r0 + ty + i * 8) * C + c0 + tx];
  __syncthreads();
#pragma unroll
  for (int i = 0; i < 4; ++i)
    op[(size_t)(c0 + ty + i * 8) * R + r0 + tx] = f2bf(tile[tx][ty + i * 8]);
}

// ---------------- gate layer 1: hg = relu(x @ Wg1 + bg1), fp32 SGEMM ----------------
__global__ __launch_bounds__(256) void k_gate1(const float* __restrict__ x,
                                               const float* __restrict__ wg1,
                                               const float* __restrict__ bg1,
                                               float* __restrict__ hg) {
  __shared__ __align__(16) float As[16][132];
  __shared__ __align__(16) float Bs[16][64];
  int bm = blockIdx.x * 128;
  int bn = blockIdx.y * 64;
  int tid = threadIdx.x;
  int tx = tid & 15, ty = tid >> 4;
  f32x4 acc[8] = {};
  for (int k0 = 0; k0 < DIM; k0 += 16) {
#pragma unroll
    for (int l = 0; l < 2; ++l) {
      int i4 = tid + l * 256;
      int row = i4 >> 2;
      int kq = (i4 & 3) * 4;
      float4 v = *(const float4*)&x[(bm + row) * DIM + k0 + kq];
      As[kq + 0][row] = v.x; As[kq + 1][row] = v.y;
      As[kq + 2][row] = v.z; As[kq + 3][row] = v.w;
    }
    {
      int krow = tid >> 4;
      int c4 = (tid & 15) * 4;
      *(float4*)&Bs[krow][c4] = *(const float4*)&wg1[(k0 + krow) * HID + bn + c4];
    }
    __syncthreads();
#pragma unroll
    for (int kk = 0; kk < 16; ++kk) {
      f32x4 a0 = *(const f32x4*)&As[kk][ty * 8];
      f32x4 a1 = *(const f32x4*)&As[kk][ty * 8 + 4];
      f32x4 bv = *(const f32x4*)&Bs[kk][tx * 4];
#pragma unroll
      for (int i = 0; i < 4; ++i) acc[i]     += bv * a0[i];
#pragma unroll
      for (int i = 0; i < 4; ++i) acc[i + 4] += bv * a1[i];
    }
    __syncthreads();
  }
  f32x4 bias = *(const f32x4*)&bg1[bn + tx * 4];
#pragma unroll
  for (int i = 0; i < 8; ++i) {
    f32x4 v = acc[i] + bias;
#pragma unroll
    for (int j = 0; j < 4; ++j) v[j] = fmaxf(v[j], 0.f);
    *(f32x4*)&hg[(bm + ty * 8 + i) * HID + bn + tx * 4] = v;
  }
}

// ---------------- gate layer 2 + softmax + top2 + routing lists ----------------
__global__ __launch_bounds__(256) void k_gate2(const float* __restrict__ hg,
                                               const float* __restrict__ wg2,
                                               const float* __restrict__ bg2,
                                               float* __restrict__ gprob,
                                               int* __restrict__ cnt,     // stride 32
                                               int* __restrict__ lists,
                                               float* __restrict__ wts) {
  __shared__ int lcnt[8];
  __shared__ int sbase[8];
  __shared__ int se1[256], se2[256], sp1[256], sp2[256];
  __shared__ float sw1[256], sw2[256];
  int tid = threadIdx.x;
  if (tid < 8) lcnt[tid] = 0;
  __syncthreads();

  int tok = blockIdx.x * 256 + tid;
  const float* hrow = hg + (size_t)tok * HID;

  float s[8];
#pragma unroll
  for (int e = 0; e < 8; ++e) s[e] = bg2[e];
#pragma unroll 8
  for (int j = 0; j < 64; ++j) {
    f32x4 hv = *(const f32x4*)(hrow + j * 4);
#pragma unroll
    for (int i = 0; i < 4; ++i) {
      const float* wr = wg2 + (j * 4 + i) * 8;
#pragma unroll
      for (int e = 0; e < 8; ++e) s[e] += hv[i] * wr[e];
    }
  }

  float m = s[0];
#pragma unroll
  for (int e = 1; e < 8; ++e) m = fmaxf(m, s[e]);
  float p[8]; float sum = 0.f;
#pragma unroll
  for (int e = 0; e < 8; ++e) { p[e] = expf(s[e] - m); sum += p[e]; }
  float inv = 1.f / sum;
#pragma unroll
  for (int e = 0; e < 8; ++e) p[e] *= inv;

  f32x4 o0 = {p[0], p[1], p[2], p[3]};
  f32x4 o1 = {p[4], p[5], p[6], p[7]};
  *(f32x4*)&gprob[(size_t)tok * 8] = o0;
  *(f32x4*)&gprob[(size_t)tok * 8 + 4] = o1;

  int e1 = 0; float p1 = p[0];
#pragma unroll
  for (int e = 1; e < 8; ++e) if (p[e] > p1) { p1 = p[e]; e1 = e; }
  int e2 = -1; float p2 = -1.f;
#pragma unroll
  for (int e = 0; e < 8; ++e) if (e != e1 && p[e] > p2) { p2 = p[e]; e2 = e; }
  float rinv = 1.f / (p1 + p2);

  int pos1 = atomicAdd(&lcnt[e1], 1);
  int pos2 = atomicAdd(&lcnt[e2], 1);
  se1[tid] = e1; sp1[tid] = pos1; sw1[tid] = p1 * rinv;
  se2[tid] = e2; sp2[tid] = pos2; sw2[tid] = p2 * rinv;
  __syncthreads();

  if (tid < 8) sbase[tid] = atomicAdd(&cnt[tid * 32], lcnt[tid]);
  __syncthreads();

  int a1i = sbase[se1[tid]] + sp1[tid];
  lists[se1[tid] * NTOK + a1i] = tok; wts[se1[tid] * NTOK + a1i] = sw1[tid];
  int a2i = sbase[se2[tid]] + sp2[tid];
  lists[se2[tid] * NTOK + a2i] = tok; wts[se2[tid] * NTOK + a2i] = sw2[tid];
}

// ---------------- expert layer 1 GEMM: h = relu(x_gathered @ W1^T + b1) ----------------
// 128x128 tile, BK=64, 4 waves, global_load_lds staging (pre-swizzled per-lane src).
__global__ __launch_bounds__(256) void k_ffn1(const unsigned short* __restrict__ xbf,
                                              const unsigned short* __restrict__ w1t,
                                              const float* __restrict__ b1,
                                              const int* __restrict__ cnt,
                                              const int* __restrict__ lists,
                                              unsigned short* __restrict__ h) {
  int e = blockIdx.z;
  int c = cnt[e * 32];
  int row0 = blockIdx.x * 128;
  if (row0 >= c) return;
  int bn = blockIdx.y * 128;
  int pfx = 0;
#pragma unroll
  for (int j = 0; j < 8; ++j) if (j < e) pfx += cnt[j * 32];

  __shared__ __align__(16) unsigned short As[128 * 64];  // 16KB
  __shared__ __align__(16) unsigned short Bs[128 * 64];  // 16KB
  __shared__ int stok[128];

  int tid = threadIdx.x;
  int lane = tid & 63;
  int wid = tid >> 6;
  int wm = wid >> 1, wn = wid & 1;
  int ar = lane & 15, kg = lane >> 4;

  if (tid < 128) stok[tid] = lists[e * NTOK + min(row0 + tid, c - 1)];
  __syncthreads();

  const unsigned short* asrc[4];
  const unsigned short* bsrc[4];
  unsigned short* ldsA[4];
  unsigned short* ldsB[4];
#pragma unroll
  for (int i = 0; i < 4; ++i) {
    int cb0 = i * 256 + wid * 64;        // wave-uniform chunk base
    int ci = cb0 + lane;
    int row = ci >> 3;
    int cb = (ci & 7) ^ (row & 7);       // inverse-swizzled source chunk
    asrc[i] = xbf + (size_t)stok[row] * DIM + cb * 8;
    bsrc[i] = w1t + ((size_t)e * HID + bn + row) * DIM + cb * 8;
    ldsA[i] = &As[cb0 * 8];
    ldsB[i] = &Bs[cb0 * 8];
  }

  f32x4 acc[4][4] = {};

  for (int kt = 0; kt < DIM / 64; ++kt) {
#pragma unroll
    for (int i = 0; i < 4; ++i) {
      gload_lds16(asrc[i] + kt * 64, ldsA[i]);
      gload_lds16(bsrc[i] + kt * 64, ldsB[i]);
    }
    __syncthreads();
#pragma unroll
    for (int ks = 0; ks < 2; ++ks) {
      int kc = ks * 4 + kg;
      s16x8 a[4], b[4];
#pragma unroll
      for (int m = 0; m < 4; ++m) {
        int row = wm * 64 + m * 16 + ar;
        a[m] = *(const s16x8*)&As[row * 64 + ((kc ^ (row & 7)) * 8)];
      }
#pragma unroll
      for (int n = 0; n < 4; ++n) {
        int row = wn * 64 + n * 16 + ar;
        b[n] = *(const s16x8*)&Bs[row * 64 + ((kc ^ (row & 7)) * 8)];
      }
#pragma unroll
      for (int m = 0; m < 4; ++m)
#pragma unroll
        for (int n = 0; n < 4; ++n)
          acc[m][n] = __builtin_amdgcn_mfma_f32_16x16x32_bf16(a[m], b[n], acc[m][n], 0, 0, 0);
    }
    __syncthreads();
  }

  // bias + relu -> h (compact pair rows, bf16); guard pad rows
  int hbase = pfx + row0;
#pragma unroll
  for (int n = 0; n < 4; ++n) {
    int col = bn + wn * 64 + n * 16 + ar;
    float bb = b1[e * HID + col];
#pragma unroll
    for (int m = 0; m < 4; ++m) {
      int rloc = wm * 64 + m * 16 + kg * 4;
#pragma unroll
      for (int r = 0; r < 4; ++r) {
        if (row0 + rloc + r < c) {
          float v = fmaxf(acc[m][n][r] + bb, 0.f);
          h[(size_t)(hbase + rloc + r) * HID + col] = f2bf(v);
        }
      }
    }
  }
}

// ---------------- expert layer 2 GEMM + weighted scatter ----------------
// out[tok] += wt * (h @ W2^T + b2). A rows contiguous (compact h), 128x128 tile, K=256.
__global__ __launch_bounds__(256) void k_ffn2(const unsigned short* __restrict__ h,
                                              const unsigned short* __restrict__ w2t,
                                              const float* __restrict__ b2,
                                              const int* __restrict__ cnt,
                                              const int* __restrict__ lists,
                                              const float* __restrict__ wts,
                                              float* __restrict__ out) {
  int e = blockIdx.z;
  int c = cnt[e * 32];
  int row0 = blockIdx.x * 128;
  if (row0 >= c) return;
  int bn = blockIdx.y * 128;
  int pfx = 0;
#pragma unroll
  for (int j = 0; j < 8; ++j) if (j < e) pfx += cnt[j * 32];

  __shared__ __align__(16) unsigned short As[128 * 64];
  __shared__ __align__(16) unsigned short Bs[128 * 64];
  __shared__ int stok[128];
  __shared__ float swt[128];

  int tid = threadIdx.x;
  int lane = tid & 63;
  int wid = tid >> 6;
  int wm = wid >> 1, wn = wid & 1;
  int ar = lane & 15, kg = lane >> 4;

  if (tid < 128) {
    int r = row0 + tid;
    stok[tid] = (r < c) ? lists[e * NTOK + r] : 0;
    swt[tid]  = (r < c) ? wts[e * NTOK + r] : 0.f;
  }
  __syncthreads();

  const unsigned short* asrc[4];
  const unsigned short* bsrc[4];
  unsigned short* ldsA[4];
  unsigned short* ldsB[4];
#pragma unroll
  for (int i = 0; i < 4; ++i) {
    int cb0 = i * 256 + wid * 64;
    int ci = cb0 + lane;
    int row = ci >> 3;
    int cb = (ci & 7) ^ (row & 7);
    asrc[i] = h + (size_t)(pfx + row0 + row) * HID + cb * 8;
    bsrc[i] = w2t + ((size_t)e * DIM + bn + row) * HID + cb * 8;
    ldsA[i] = &As[cb0 * 8];
    ldsB[i] = &Bs[cb0 * 8];
  }

  f32x4 acc[4][4] = {};

  for (int kt = 0; kt < HID / 64; ++kt) {
#pragma unroll
    for (int i = 0; i < 4; ++i) {
      gload_lds16(asrc[i] + kt * 64, ldsA[i]);
      gload_lds16(bsrc[i] + kt * 64, ldsB[i]);
    }
    __syncthreads();
#pragma unroll
    for (int ks = 0; ks < 2; ++ks) {
      int kc = ks * 4 + kg;
      s16x8 a[4], b[4];
#pragma unroll
      for (int m = 0; m < 4; ++m) {
        int row = wm * 64 + m * 16 + ar;
        a[m] = *(const s16x8*)&As[row * 64 + ((kc ^ (row & 7)) * 8)];
      }
#pragma unroll
      for (int n = 0; n < 4; ++n) {
        int row = wn * 64 + n * 16 + ar;
        b[n] = *(const s16x8*)&Bs[row * 64 + ((kc ^ (row & 7)) * 8)];
      }
#pragma unroll
      for (int m = 0; m < 4; ++m)
#pragma unroll
        for (int n = 0; n < 4; ++n)
          acc[m][n] = __builtin_amdgcn_mfma_f32_16x16x32_bf16(a[m], b[n], acc[m][n], 0, 0, 0);
    }
    __syncthreads();
  }

  // epilogue: weighted atomic scatter
#pragma unroll
  for (int n = 0; n < 4; ++n) {
    int col = bn + wn * 64 + n * 16 + ar;
    float bb = b2[e * DIM + col];
#pragma unroll
    for (int m = 0; m < 4; ++m) {
      int rloc = wm * 64 + m * 16 + kg * 4;
#pragma unroll
      for (int r = 0; r < 4; ++r) {
        float w = swt[rloc + r];
        if (w != 0.f) {
          float v = (acc[m][n][r] + bb) * w;
          atomicAdd(&out[(size_t)stok[rloc + r] * DIM + col], v);
        }
      }
    }
  }
}

extern "C" void kernel_launch(void* const* d_in, const int* in_sizes, int n_in,
                              void* d_out, int out_size, void* d_ws, size_t ws_size,
                              hipStream_t stream) {
  const float* x   = (const float*)d_in[0];
  const float* W1  = (const float*)d_in[1];
  const float* b1  = (const float*)d_in[2];
  const float* W2  = (const float*)d_in[3];
  const float* b2  = (const float*)d_in[4];
  const float* Wg1 = (const float*)d_in[5];
  const float* bg1 = (const float*)d_in[6];
  const float* Wg2 = (const float*)d_in[7];
  const float* bg2 = (const float*)d_in[8];
  float* out = (float*)d_out;                       // [N][768] then [N][8]
  float* gprob = out + (size_t)NTOK * DIM;

  char* ws = (char*)d_ws;
  size_t off = 0;
  auto alloc = [&](size_t bytes) { void* pp = ws + off; off += (bytes + 255) & ~(size_t)255; return pp; };
  unsigned short* xbf = (unsigned short*)alloc((size_t)NTOK * DIM * 2);
  unsigned short* w1t = (unsigned short*)alloc((size_t)NEXP * HID * DIM * 2);
  unsigned short* w2t = (unsigned short*)alloc((size_t)NEXP * DIM * HID * 2);
  float* hg = (float*)alloc((size_t)NTOK * HID * 4);
  int* cnt = (int*)alloc(NEXP * 32 * 4);            // 128B-padded counters
  int* lists = (int*)alloc((size_t)NEXP * NTOK * 4);
  float* wts = (float*)alloc((size_t)NEXP * NTOK * 4);

  // h (65536 compact pair rows x 256 bf16 = 32MB) reuses hg's 32MB:
  // k_gate2 (reads hg) completes before k_ffn1 (writes h) in stream order.
  unsigned short* h = (unsigned short*)hg;

  hipMemsetAsync(d_out, 0, (size_t)NTOK * DIM * sizeof(float), stream);
  hipMemsetAsync(cnt, 0, NEXP * 32 * sizeof(int), stream);

  k_cvt_x<<<(NTOK * DIM) / (256 * 8), 256, 0, stream>>>(x, xbf);
  k_tr<<<dim3(HID / 32, DIM / 32, NEXP), 256, 0, stream>>>(W1, w1t, DIM, HID);  // -> w1t[e][h][d]
  k_tr<<<dim3(DIM / 32, HID / 32, NEXP), 256, 0, stream>>>(W2, w2t, HID, DIM);  // -> w2t[e][d][h]
  k_gate1<<<dim3(NTOK / 128, HID / 64), 256, 0, stream>>>(x, Wg1, bg1, hg);
  k_gate2<<<NTOK / 256, 256, 0, stream>>>(hg, Wg2, bg2, gprob, cnt, lists, wts);
  k_ffn1<<<dim3(NTOK / 128, 2, NEXP), 256, 0, stream>>>(xbf, w1t, b1, cnt, lists, h);
  k_ffn2<<<dim3(NTOK / 128, 6, NEXP), 256, 0, stream>>>(h, w2t, b2, cnt, lists, wts, out);
}

// Round 5
// 446.089 us; speedup vs baseline: 2.6921x; 1.2615x over previous
//
#include <hip/hip_runtime.h>
#include <hip/hip_bf16.h>
#include <stdint.h>

#define NTOK 32768
#define DIM  768
#define HID  256
#define NEXP 8

typedef float f32x4 __attribute__((ext_vector_type(4)));
typedef short s16x8 __attribute__((ext_vector_type(8)));

__device__ __forceinline__ unsigned short f2bf(float f) {
  union { float f; unsigned int u; } c; c.f = f;
  unsigned int r = c.u + 0x7fffu + ((c.u >> 16) & 1u);
  return (unsigned short)(r >> 16);
}

__device__ __forceinline__ float bf2f(unsigned int u) {
  union { unsigned int x; float f; } c; c.x = u << 16; return c.f;
}

// async global -> LDS, 16B per lane. LDS dest is wave-uniform base + lane*16.
__device__ __forceinline__ void gload_lds16(const unsigned short* g, unsigned short* l) {
  __builtin_amdgcn_global_load_lds((const __attribute__((address_space(1))) void*)g,
                                   (__attribute__((address_space(3))) void*)l, 16, 0, 0);
}

// ---------------- x fp32 -> bf16 ----------------
__global__ __launch_bounds__(256) void k_cvt_x(const float* __restrict__ x,
                                               unsigned short* __restrict__ xbf) {
  int i = (blockIdx.x * 256 + threadIdx.x) * 8;
  float4 a = *(const float4*)(x + i);
  float4 b = *(const float4*)(x + i + 4);
  unsigned int p0 = (unsigned int)f2bf(a.x) | ((unsigned int)f2bf(a.y) << 16);
  unsigned int p1 = (unsigned int)f2bf(a.z) | ((unsigned int)f2bf(a.w) << 16);
  unsigned int p2 = (unsigned int)f2bf(b.x) | ((unsigned int)f2bf(b.y) << 16);
  unsigned int p3 = (unsigned int)f2bf(b.z) | ((unsigned int)f2bf(b.w) << 16);
  int4 v; v.x = (int)p0; v.y = (int)p1; v.z = (int)p2; v.w = (int)p3;
  *(int4*)(xbf + i) = v;
}

// ---------------- fp32 [R][C] -> bf16 [C][R] transpose via LDS tile ----------------
__global__ __launch_bounds__(256) void k_tr(const float* __restrict__ in,
                                            unsigned short* __restrict__ outp,
                                            int R, int C) {
  __shared__ float tile[32][33];
  int e = blockIdx.z;
  const float* ip = in + (size_t)e * R * C;
  unsigned short* op = outp + (size_t)e * R * C;
  int tx = threadIdx.x & 31, ty = threadIdx.x >> 5;  // 32x8
  int r0 = blockIdx.y * 32, c0 = blockIdx.x * 32;
#pragma unroll
  for (int i = 0; i < 4; ++i)
    tile[ty + i * 8][tx] = ip[(size_t)(r0 + ty + i * 8) * C + c0 + tx];
  __syncthreads();
#pragma unroll
  for (int i = 0; i < 4; ++i)
    op[(size_t)(c0 + ty + i * 8) * R + r0 + tx] = f2bf(tile[tx][ty + i * 8]);
}

// ---------------- gate layer 1: hg = relu(x @ Wg1 + bg1), fp32 SGEMM ----------------
__global__ __launch_bounds__(256) void k_gate1(const float* __restrict__ x,
                                               const float* __restrict__ wg1,
                                               const float* __restrict__ bg1,
                                               float* __restrict__ hg) {
  __shared__ __align__(16) float As[16][132];
  __shared__ __align__(16) float Bs[16][64];
  int bm = blockIdx.x * 128;
  int bn = blockIdx.y * 64;
  int tid = threadIdx.x;
  int tx = tid & 15, ty = tid >> 4;
  f32x4 acc[8] = {};
  for (int k0 = 0; k0 < DIM; k0 += 16) {
#pragma unroll
    for (int l = 0; l < 2; ++l) {
      int i4 = tid + l * 256;
      int row = i4 >> 2;
      int kq = (i4 & 3) * 4;
      float4 v = *(const float4*)&x[(bm + row) * DIM + k0 + kq];
      As[kq + 0][row] = v.x; As[kq + 1][row] = v.y;
      As[kq + 2][row] = v.z; As[kq + 3][row] = v.w;
    }
    {
      int krow = tid >> 4;
      int c4 = (tid & 15) * 4;
      *(float4*)&Bs[krow][c4] = *(const float4*)&wg1[(k0 + krow) * HID + bn + c4];
    }
    __syncthreads();
#pragma unroll
    for (int kk = 0; kk < 16; ++kk) {
      f32x4 a0 = *(const f32x4*)&As[kk][ty * 8];
      f32x4 a1 = *(const f32x4*)&As[kk][ty * 8 + 4];
      f32x4 bv = *(const f32x4*)&Bs[kk][tx * 4];
#pragma unroll
      for (int i = 0; i < 4; ++i) acc[i]     += bv * a0[i];
#pragma unroll
      for (int i = 0; i < 4; ++i) acc[i + 4] += bv * a1[i];
    }
    __syncthreads();
  }
  f32x4 bias = *(const f32x4*)&bg1[bn + tx * 4];
#pragma unroll
  for (int i = 0; i < 8; ++i) {
    f32x4 v = acc[i] + bias;
#pragma unroll
    for (int j = 0; j < 4; ++j) v[j] = fmaxf(v[j], 0.f);
    *(f32x4*)&hg[(bm + ty * 8 + i) * HID + bn + tx * 4] = v;
  }
}

// ---------------- gate layer 2 + softmax + top2 + routing lists ----------------
// wts sign-encodes rank: +w for top-1 expert entry, -w for top-2 entry.
__global__ __launch_bounds__(256) void k_gate2(const float* __restrict__ hg,
                                               const float* __restrict__ wg2,
                                               const float* __restrict__ bg2,
                                               float* __restrict__ gprob,
                                               int* __restrict__ cnt,     // stride 32
                                               int* __restrict__ lists,
                                               float* __restrict__ wts) {
  __shared__ int lcnt[8];
  __shared__ int sbase[8];
  __shared__ int se1[256], se2[256], sp1[256], sp2[256];
  __shared__ float sw1[256], sw2[256];
  int tid = threadIdx.x;
  if (tid < 8) lcnt[tid] = 0;
  __syncthreads();

  int tok = blockIdx.x * 256 + tid;
  const float* hrow = hg + (size_t)tok * HID;

  float s[8];
#pragma unroll
  for (int e = 0; e < 8; ++e) s[e] = bg2[e];
#pragma unroll 8
  for (int j = 0; j < 64; ++j) {
    f32x4 hv = *(const f32x4*)(hrow + j * 4);
#pragma unroll
    for (int i = 0; i < 4; ++i) {
      const float* wr = wg2 + (j * 4 + i) * 8;
#pragma unroll
      for (int e = 0; e < 8; ++e) s[e] += hv[i] * wr[e];
    }
  }

  float m = s[0];
#pragma unroll
  for (int e = 1; e < 8; ++e) m = fmaxf(m, s[e]);
  float p[8]; float sum = 0.f;
#pragma unroll
  for (int e = 0; e < 8; ++e) { p[e] = expf(s[e] - m); sum += p[e]; }
  float inv = 1.f / sum;
#pragma unroll
  for (int e = 0; e < 8; ++e) p[e] *= inv;

  f32x4 o0 = {p[0], p[1], p[2], p[3]};
  f32x4 o1 = {p[4], p[5], p[6], p[7]};
  *(f32x4*)&gprob[(size_t)tok * 8] = o0;
  *(f32x4*)&gprob[(size_t)tok * 8 + 4] = o1;

  int e1 = 0; float p1 = p[0];
#pragma unroll
  for (int e = 1; e < 8; ++e) if (p[e] > p1) { p1 = p[e]; e1 = e; }
  int e2 = -1; float p2 = -1.f;
#pragma unroll
  for (int e = 0; e < 8; ++e) if (e != e1 && p[e] > p2) { p2 = p[e]; e2 = e; }
  float rinv = 1.f / (p1 + p2);

  int pos1 = atomicAdd(&lcnt[e1], 1);
  int pos2 = atomicAdd(&lcnt[e2], 1);
  se1[tid] = e1; sp1[tid] = pos1; sw1[tid] = p1 * rinv;
  se2[tid] = e2; sp2[tid] = pos2; sw2[tid] = p2 * rinv;
  __syncthreads();

  if (tid < 8) sbase[tid] = atomicAdd(&cnt[tid * 32], lcnt[tid]);
  __syncthreads();

  int a1i = sbase[se1[tid]] + sp1[tid];
  lists[se1[tid] * NTOK + a1i] = tok; wts[se1[tid] * NTOK + a1i] = sw1[tid];   // rank0: +w
  int a2i = sbase[se2[tid]] + sp2[tid];
  lists[se2[tid] * NTOK + a2i] = tok; wts[se2[tid] * NTOK + a2i] = -sw2[tid];  // rank1: -w
}

// ---------------- expert layer 1 GEMM: h = relu(x_gathered @ W1^T + b1) ----------------
__global__ __launch_bounds__(256) void k_ffn1(const unsigned short* __restrict__ xbf,
                                              const unsigned short* __restrict__ w1t,
                                              const float* __restrict__ b1,
                                              const int* __restrict__ cnt,
                                              const int* __restrict__ lists,
                                              unsigned short* __restrict__ h) {
  int e = blockIdx.z;
  int c = cnt[e * 32];
  int row0 = blockIdx.x * 128;
  if (row0 >= c) return;
  int bn = blockIdx.y * 128;
  int pfx = 0;
#pragma unroll
  for (int j = 0; j < 8; ++j) if (j < e) pfx += cnt[j * 32];

  __shared__ __align__(16) unsigned short As[128 * 64];  // 16KB
  __shared__ __align__(16) unsigned short Bs[128 * 64];  // 16KB
  __shared__ int stok[128];

  int tid = threadIdx.x;
  int lane = tid & 63;
  int wid = tid >> 6;
  int wm = wid >> 1, wn = wid & 1;
  int ar = lane & 15, kg = lane >> 4;

  if (tid < 128) stok[tid] = lists[e * NTOK + min(row0 + tid, c - 1)];
  __syncthreads();

  const unsigned short* asrc[4];
  const unsigned short* bsrc[4];
  unsigned short* ldsA[4];
  unsigned short* ldsB[4];
#pragma unroll
  for (int i = 0; i < 4; ++i) {
    int cb0 = i * 256 + wid * 64;        // wave-uniform chunk base
    int ci = cb0 + lane;
    int row = ci >> 3;
    int cb = (ci & 7) ^ (row & 7);       // inverse-swizzled source chunk
    asrc[i] = xbf + (size_t)stok[row] * DIM + cb * 8;
    bsrc[i] = w1t + ((size_t)e * HID + bn + row) * DIM + cb * 8;
    ldsA[i] = &As[cb0 * 8];
    ldsB[i] = &Bs[cb0 * 8];
  }

  f32x4 acc[4][4] = {};

  for (int kt = 0; kt < DIM / 64; ++kt) {
#pragma unroll
    for (int i = 0; i < 4; ++i) {
      gload_lds16(asrc[i] + kt * 64, ldsA[i]);
      gload_lds16(bsrc[i] + kt * 64, ldsB[i]);
    }
    __syncthreads();
#pragma unroll
    for (int ks = 0; ks < 2; ++ks) {
      int kc = ks * 4 + kg;
      s16x8 a[4], b[4];
#pragma unroll
      for (int m = 0; m < 4; ++m) {
        int row = wm * 64 + m * 16 + ar;
        a[m] = *(const s16x8*)&As[row * 64 + ((kc ^ (row & 7)) * 8)];
      }
#pragma unroll
      for (int n = 0; n < 4; ++n) {
        int row = wn * 64 + n * 16 + ar;
        b[n] = *(const s16x8*)&Bs[row * 64 + ((kc ^ (row & 7)) * 8)];
      }
#pragma unroll
      for (int m = 0; m < 4; ++m)
#pragma unroll
        for (int n = 0; n < 4; ++n)
          acc[m][n] = __builtin_amdgcn_mfma_f32_16x16x32_bf16(a[m], b[n], acc[m][n], 0, 0, 0);
    }
    __syncthreads();
  }

  // bias + relu -> h (compact pair rows, bf16); guard pad rows
  int hbase = pfx + row0;
#pragma unroll
  for (int n = 0; n < 4; ++n) {
    int col = bn + wn * 64 + n * 16 + ar;
    float bb = b1[e * HID + col];
#pragma unroll
    for (int m = 0; m < 4; ++m) {
      int rloc = wm * 64 + m * 16 + kg * 4;
#pragma unroll
      for (int r = 0; r < 4; ++r) {
        if (row0 + rloc + r < c) {
          float v = fmaxf(acc[m][n][r] + bb, 0.f);
          h[(size_t)(hbase + rloc + r) * HID + col] = f2bf(v);
        }
      }
    }
  }
}

// ---------------- expert layer 2 GEMM + rank-split partial store (or atomic fallback) ----------------
template <bool STORE_PART>
__global__ __launch_bounds__(256) void k_ffn2(const unsigned short* __restrict__ h,
                                              const unsigned short* __restrict__ w2t,
                                              const float* __restrict__ b2,
                                              const int* __restrict__ cnt,
                                              const int* __restrict__ lists,
                                              const float* __restrict__ wts,
                                              unsigned short* __restrict__ part0,
                                              unsigned short* __restrict__ part1,
                                              float* __restrict__ out) {
  int e = blockIdx.z;
  int c = cnt[e * 32];
  int row0 = blockIdx.x * 128;
  if (row0 >= c) return;
  int bn = blockIdx.y * 128;
  int pfx = 0;
#pragma unroll
  for (int j = 0; j < 8; ++j) if (j < e) pfx += cnt[j * 32];

  __shared__ __align__(16) unsigned short As[128 * 64];
  __shared__ __align__(16) unsigned short Bs[128 * 64];
  __shared__ int stok[128];
  __shared__ float swt[128];

  int tid = threadIdx.x;
  int lane = tid & 63;
  int wid = tid >> 6;
  int wm = wid >> 1, wn = wid & 1;
  int ar = lane & 15, kg = lane >> 4;

  if (tid < 128) {
    int r = row0 + tid;
    stok[tid] = (r < c) ? lists[e * NTOK + r] : 0;
    swt[tid]  = (r < c) ? wts[e * NTOK + r] : 0.f;
  }
  __syncthreads();

  const unsigned short* asrc[4];
  const unsigned short* bsrc[4];
  unsigned short* ldsA[4];
  unsigned short* ldsB[4];
#pragma unroll
  for (int i = 0; i < 4; ++i) {
    int cb0 = i * 256 + wid * 64;
    int ci = cb0 + lane;
    int row = ci >> 3;
    int cb = (ci & 7) ^ (row & 7);
    asrc[i] = h + (size_t)(pfx + row0 + row) * HID + cb * 8;
    bsrc[i] = w2t + ((size_t)e * DIM + bn + row) * HID + cb * 8;
    ldsA[i] = &As[cb0 * 8];
    ldsB[i] = &Bs[cb0 * 8];
  }

  f32x4 acc[4][4] = {};

  for (int kt = 0; kt < HID / 64; ++kt) {
#pragma unroll
    for (int i = 0; i < 4; ++i) {
      gload_lds16(asrc[i] + kt * 64, ldsA[i]);
      gload_lds16(bsrc[i] + kt * 64, ldsB[i]);
    }
    __syncthreads();
#pragma unroll
    for (int ks = 0; ks < 2; ++ks) {
      int kc = ks * 4 + kg;
      s16x8 a[4], b[4];
#pragma unroll
      for (int m = 0; m < 4; ++m) {
        int row = wm * 64 + m * 16 + ar;
        a[m] = *(const s16x8*)&As[row * 64 + ((kc ^ (row & 7)) * 8)];
      }
#pragma unroll
      for (int n = 0; n < 4; ++n) {
        int row = wn * 64 + n * 16 + ar;
        b[n] = *(const s16x8*)&Bs[row * 64 + ((kc ^ (row & 7)) * 8)];
      }
#pragma unroll
      for (int m = 0; m < 4; ++m)
#pragma unroll
        for (int n = 0; n < 4; ++n)
          acc[m][n] = __builtin_amdgcn_mfma_f32_16x16x32_bf16(a[m], b[n], acc[m][n], 0, 0, 0);
    }
    __syncthreads();
  }

  // epilogue: each (token,rank) row is written by exactly one block -> plain stores
#pragma unroll
  for (int n = 0; n < 4; ++n) {
    int col = bn + wn * 64 + n * 16 + ar;
    float bb = b2[e * DIM + col];
#pragma unroll
    for (int m = 0; m < 4; ++m) {
      int rloc = wm * 64 + m * 16 + kg * 4;
#pragma unroll
      for (int r = 0; r < 4; ++r) {
        float w = swt[rloc + r];
        if (w != 0.f) {
          float v = (acc[m][n][r] + bb) * fabsf(w);
          if constexpr (STORE_PART) {
            unsigned short* dst = (w > 0.f) ? part0 : part1;
            dst[(size_t)stok[rloc + r] * DIM + col] = f2bf(v);
          } else {
            atomicAdd(&out[(size_t)stok[rloc + r] * DIM + col], v);
          }
        }
      }
    }
  }
}

// ---------------- combine: out = part0 + part1 (streaming) ----------------
__global__ __launch_bounds__(256) void k_combine(const unsigned short* __restrict__ p0,
                                                 const unsigned short* __restrict__ p1,
                                                 float* __restrict__ out) {
  size_t i = ((size_t)blockIdx.x * 256 + threadIdx.x) * 8;
  int4 a = *(const int4*)(p0 + i);
  int4 b = *(const int4*)(p1 + i);
  unsigned int ua[4] = {(unsigned)a.x, (unsigned)a.y, (unsigned)a.z, (unsigned)a.w};
  unsigned int ub[4] = {(unsigned)b.x, (unsigned)b.y, (unsigned)b.z, (unsigned)b.w};
  float o[8];
#pragma unroll
  for (int q = 0; q < 4; ++q) {
    o[q * 2 + 0] = bf2f(ua[q] & 0xffffu) + bf2f(ub[q] & 0xffffu);
    o[q * 2 + 1] = bf2f(ua[q] >> 16)     + bf2f(ub[q] >> 16);
  }
  *(float4*)(out + i)     = *(float4*)&o[0];
  *(float4*)(out + i + 4) = *(float4*)&o[4];
}

extern "C" void kernel_launch(void* const* d_in, const int* in_sizes, int n_in,
                              void* d_out, int out_size, void* d_ws, size_t ws_size,
                              hipStream_t stream) {
  const float* x   = (const float*)d_in[0];
  const float* W1  = (const float*)d_in[1];
  const float* b1  = (const float*)d_in[2];
  const float* W2  = (const float*)d_in[3];
  const float* b2  = (const float*)d_in[4];
  const float* Wg1 = (const float*)d_in[5];
  const float* bg1 = (const float*)d_in[6];
  const float* Wg2 = (const float*)d_in[7];
  const float* bg2 = (const float*)d_in[8];
  float* out = (float*)d_out;                       // [N][768] then [N][8]
  float* gprob = out + (size_t)NTOK * DIM;

  char* ws = (char*)d_ws;
  size_t off = 0;
  auto alloc = [&](size_t bytes) { void* pp = ws + off; off += (bytes + 255) & ~(size_t)255; return pp; };
  unsigned short* xbf = (unsigned short*)alloc((size_t)NTOK * DIM * 2);
  unsigned short* w1t = (unsigned short*)alloc((size_t)NEXP * HID * DIM * 2);
  unsigned short* w2t = (unsigned short*)alloc((size_t)NEXP * DIM * HID * 2);
  float* hg = (float*)alloc((size_t)NTOK * HID * 4);
  int* cnt = (int*)alloc(NEXP * 32 * 4);            // 128B-padded counters
  int* lists = (int*)alloc((size_t)NEXP * NTOK * 4);
  float* wts = (float*)alloc((size_t)NEXP * NTOK * 4);
  unsigned short* part0 = (unsigned short*)alloc((size_t)NTOK * DIM * 2);
  unsigned short* part1 = (unsigned short*)alloc((size_t)NTOK * DIM * 2);
  bool store_mode = (off <= ws_size);

  // h (65536 compact rows x 256 bf16 = 32MB) reuses hg's 32MB (gate2 finishes first).
  unsigned short* h = (unsigned short*)hg;

  hipMemsetAsync(cnt, 0, NEXP * 32 * sizeof(int), stream);
  if (!store_mode)
    hipMemsetAsync(d_out, 0, (size_t)NTOK * DIM * sizeof(float), stream);

  k_cvt_x<<<(NTOK * DIM) / (256 * 8), 256, 0, stream>>>(x, xbf);
  k_tr<<<dim3(HID / 32, DIM / 32, NEXP), 256, 0, stream>>>(W1, w1t, DIM, HID);  // -> w1t[e][h][d]
  k_tr<<<dim3(DIM / 32, HID / 32, NEXP), 256, 0, stream>>>(W2, w2t, HID, DIM);  // -> w2t[e][d][h]
  k_gate1<<<dim3(NTOK / 128, HID / 64), 256, 0, stream>>>(x, Wg1, bg1, hg);
  k_gate2<<<NTOK / 256, 256, 0, stream>>>(hg, Wg2, bg2, gprob, cnt, lists, wts);
  k_ffn1<<<dim3(NTOK / 128, 2, NEXP), 256, 0, stream>>>(xbf, w1t, b1, cnt, lists, h);
  if (store_mode) {
    k_ffn2<true><<<dim3(NTOK / 128, 6, NEXP), 256, 0, stream>>>(h, w2t, b2, cnt, lists, wts, part0, part1, out);
    k_combine<<<(NTOK * DIM) / (256 * 8), 256, 0, stream>>>(part0, part1, out);
  } else {
    k_ffn2<false><<<dim3(NTOK / 128, 6, NEXP), 256, 0, stream>>>(h, w2t, b2, cnt, lists, wts, part0, part1, out);
  }
}